// Round 8
// baseline (76.286 us; speedup 1.0000x reference)
//
#include <hip/hip_runtime.h>

#define NB 4
#define NCI 64
#define NCO 64
#define NH 256
#define NW 256
#define NIMG (NB*NCI)      // 256
#define PLANE (NIMG*NH)    // 65536

// workspace offsets (in floats)
#define OF_COS 0
#define OF_SIN 256
#define OF_TW  512                      // [30][256] final-stage trig (ky=1..15 cos/sin)
#define OF_XW  16384                    // Xw: [img][32 cols][256 rows]
#define OF_XS_RE (OF_XW + 32*PLANE)
#define OF_XS_IM (OF_XS_RE + PLANE)
#define OF_O1_RE (OF_XS_IM + PLANE)
#define OF_O1_IM (OF_O1_RE + PLANE)
#define OF_O2_RE (OF_O1_IM + PLANE)
#define OF_O2_IM (OF_O2_RE + PLANE)

// grid 31: block 0 -> cos/sin tables; blocks 1..30 -> one TW row each
__global__ __launch_bounds__(256) void k0_init(float* __restrict__ ws) {
  const int t = threadIdx.x, b = blockIdx.x;
  const double TP = 6.283185307179586;
  if (b == 0) {
    double a = TP * t / 256.0;
    ws[OF_COS + t] = (float)cos(a);
    ws[OF_SIN + t] = (float)sin(a);
  } else {
    const int p = b - 1;              // 0..29
    const int ky = (p >> 1) + 1;
    double a = TP * ((ky * t) & 255) / 256.0;
    ws[OF_TW + p*256 + t] = (p & 1) ? (float)sin(a) : (float)cos(a);
  }
}

// Stage 1: w-DFT per row. One block per image. Rotation recurrence for trig,
// (w, w+128) folding halves FMAs. Xw out: [img][col][row], col<16: Re(ky),
// col>=16: Im(ky-16).   [R5-measured: ~15 us]
__global__ __launch_bounds__(256) void k1_dftw(const float* __restrict__ x,
                                               float* __restrict__ ws) {
  __shared__ float xT[64*260];         // [w-col 0..63][row 0..255], pad 260
  __shared__ float cst[256], snt[256];
  const int t = threadIdx.x;
  const int img = blockIdx.x;

  cst[t] = ws[OF_COS + t];
  snt[t] = ws[OF_SIN + t];

  const int l8 = t & 7, r5 = t >> 3;   // staging: 16B-slot, row-group
  const int g  = t & 3, tr = t >> 2;   // compute: ky-group, row-quad
  const int ky0 = g * 4;

  __syncthreads();

  float cd[4], sd[4];                  // per-ky rotation step
#pragma unroll
  for (int kl = 0; kl < 4; ++kl) {
    cd[kl] = cst[ky0 + kl];
    sd[kl] = snt[ky0 + kl];
  }

  float ar[4][4], ai[4][4];            // [kl][row]
#pragma unroll
  for (int kl = 0; kl < 4; ++kl)
#pragma unroll
    for (int r = 0; r < 4; ++r) { ar[kl][r] = 0.f; ai[kl][r] = 0.f; }

  const float* xb = x + (size_t)img * 65536;
  float4 v[16];
#pragma unroll
  for (int jj = 0; jj < 8; ++jj) {
    const int row = r5 + 32*jj;
    v[jj]   = *(const float4*)(xb + row*256 + l8*4);
    v[8+jj] = *(const float4*)(xb + row*256 + 128 + l8*4);
  }

  for (int c = 0; c < 4; ++c) {
    __syncthreads();
#pragma unroll
    for (int jj = 0; jj < 8; ++jj) {
      const int row = r5 + 32*jj;
      xT[(l8*4+0)*260 + row] = v[jj].x;
      xT[(l8*4+1)*260 + row] = v[jj].y;
      xT[(l8*4+2)*260 + row] = v[jj].z;
      xT[(l8*4+3)*260 + row] = v[jj].w;
      xT[(32+l8*4+0)*260 + row] = v[8+jj].x;
      xT[(32+l8*4+1)*260 + row] = v[8+jj].y;
      xT[(32+l8*4+2)*260 + row] = v[8+jj].z;
      xT[(32+l8*4+3)*260 + row] = v[8+jj].w;
    }
    __syncthreads();
    if (c < 3) {                       // T14: issue next chunk loads now
      const int w0n = (c+1) * 32;
#pragma unroll
      for (int jj = 0; jj < 8; ++jj) {
        const int row = r5 + 32*jj;
        v[jj]   = *(const float4*)(xb + row*256 + w0n + l8*4);
        v[8+jj] = *(const float4*)(xb + row*256 + w0n + 128 + l8*4);
      }
    }
    float cc[4], sv[4];
#pragma unroll
    for (int kl = 0; kl < 4; ++kl) {
      const int m = ((ky0 + kl) * c * 32) & 255;
      cc[kl] = cst[m];
      sv[kl] = snt[m];
    }
#pragma unroll 8
    for (int wl = 0; wl < 32; ++wl) {
      const float4 xlo = *(const float4*)&xT[wl*260 + tr*4];
      const float4 xhi = *(const float4*)&xT[(wl+32)*260 + tr*4];
      const float xe0 = xlo.x + xhi.x, xo0 = xlo.x - xhi.x;
      const float xe1 = xlo.y + xhi.y, xo1 = xlo.y - xhi.y;
      const float xe2 = xlo.z + xhi.z, xo2 = xlo.z - xhi.z;
      const float xe3 = xlo.w + xhi.w, xo3 = xlo.w - xhi.w;
#pragma unroll
      for (int kl = 0; kl < 4; ++kl) {
        const float s0 = (kl & 1) ? xo0 : xe0;
        const float s1 = (kl & 1) ? xo1 : xe1;
        const float s2 = (kl & 1) ? xo2 : xe2;
        const float s3 = (kl & 1) ? xo3 : xe3;
        ar[kl][0] += s0 * cc[kl];  ai[kl][0] -= s0 * sv[kl];
        ar[kl][1] += s1 * cc[kl];  ai[kl][1] -= s1 * sv[kl];
        ar[kl][2] += s2 * cc[kl];  ai[kl][2] -= s2 * sv[kl];
        ar[kl][3] += s3 * cc[kl];  ai[kl][3] -= s3 * sv[kl];
        const float nc = cc[kl]*cd[kl] - sv[kl]*sd[kl];
        const float ns = sv[kl]*cd[kl] + cc[kl]*sd[kl];
        cc[kl] = nc; sv[kl] = ns;
      }
    }
  }
  float* Xw = ws + OF_XW + (size_t)img * 8192;
#pragma unroll
  for (int kl = 0; kl < 4; ++kl) {
    const int ky = ky0 + kl;
    float4 sr; sr.x = ar[kl][0]; sr.y = ar[kl][1]; sr.z = ar[kl][2]; sr.w = ar[kl][3];
    float4 si; si.x = ai[kl][0]; si.y = ai[kl][1]; si.z = ai[kl][2]; si.w = ai[kl][3];
    *(float4*)&Xw[ky*256 + tr*4]      = sr;
    *(float4*)&Xw[(16+ky)*256 + tr*4] = si;
  }
}

// Stage 2: xs[img][kx*16+ky] = sum_h Xw[img][.][h] * e^{-2pi i kx h/256}
// [R5-measured: ~5 us]
__global__ __launch_bounds__(256) void k2_dfth(float* __restrict__ ws) {
  __shared__ float L[32*257];   // [plane][h], pad 257
  const int t = threadIdx.x, img = blockIdx.x;
  const float* XwI = ws + OF_XW + (size_t)img * 8192;
  for (int p = 0; p < 32; ++p)
    L[p*257 + t] = XwI[p*256 + t];
  __syncthreads();
  const int kx = t >> 4, ky = t & 15;
  const float cdk = ws[OF_COS + kx];
  const float sdk = ws[OF_SIN + kx];
  float c = 1.f, s = 0.f, arr = 0.f, aii = 0.f;
#pragma unroll 4
  for (int h = 0; h < 256; ++h) {
    const float xr = L[ky*257 + h];
    const float xi = L[(16+ky)*257 + h];
    arr += xr*c + xi*s;
    aii += xi*c - xr*s;
    const float nc = c*cdk - s*sdk;
    const float ns = s*cdk + c*sdk;
    c = nc; s = ns;
  }
  ws[OF_XS_RE + img*256 + t] = arr;
  ws[OF_XS_IM + img*256 + t] = aii;
}

// Stage 3: o1/o2[b,o,m] = sum_i xs[b,i,m] * (wr + i wi)[i,o,m]
__global__ __launch_bounds__(256) void k3_mix(const float* __restrict__ w1r,
    const float* __restrict__ w1i, const float* __restrict__ w2r,
    const float* __restrict__ w2i, float* __restrict__ ws) {
  const int o  = blockIdx.x;     // 0..63
  const int mc = blockIdx.y;     // 0..3
  const int t  = threadIdx.x;    // 256
  const int b  = t >> 6;
  const int m  = (mc << 6) + (t & 63);
  const float* xsr = ws + OF_XS_RE;
  const float* xsi = ws + OF_XS_IM;
  float a1r=0.f, a1i=0.f, a2r=0.f, a2i=0.f;
#pragma unroll 4
  for (int i = 0; i < NCI; ++i) {
    const float xr = xsr[((b*NCI + i) << 8) + m];
    const float xi = xsi[((b*NCI + i) << 8) + m];
    const int wi = ((i*NCO + o) << 8) + m;
    const float p = w1r[wi], q = w1i[wi], u = w2r[wi], v = w2i[wi];
    a1r += xr*p - xi*q;
    a1i += xr*q + xi*p;
    a2r += xr*u - xi*v;
    a2i += xr*v + xi*u;
  }
  const int oi = ((b*NCO + o) << 8) + m;
  ws[OF_O1_RE + oi] = a1r;
  ws[OF_O1_IM + oi] = a1i;
  ws[OF_O2_RE + oi] = a2r;
  ws[OF_O2_IM + oi] = a2i;
}

// Fused stage 4+5, grid 2048 = (bo 256) x (hc 8: 32 rows each), 8 blocks/CU.
// phase A: thread (hl 0..31, kq 0..7) computes S[hl][kq*2..+1] via dual rotation.
// phase B: radix-4 butterfly over ky mod 4 -> 4 columns per thread; 8 rows/wave.
__global__ __launch_bounds__(256) void k45_idft(const float* __restrict__ ws,
                                                float* __restrict__ out) {
  __shared__ __align__(16) float o1r[256], o1i[256], o2r[256], o2i[256];
  __shared__ float cst[256], snt[256];
  __shared__ __align__(16) float Sr[32][20], Si[32][20];
  const int t  = threadIdx.x;
  const int bo = blockIdx.x >> 3;
  const int hc = blockIdx.x & 7;

  o1r[t] = ws[OF_O1_RE + bo*256 + t];
  o1i[t] = ws[OF_O1_IM + bo*256 + t];
  o2r[t] = ws[OF_O2_RE + bo*256 + t];
  o2i[t] = ws[OF_O2_IM + bo*256 + t];
  cst[t] = ws[OF_COS + t];
  snt[t] = ws[OF_SIN + t];

  const int w0 = t & 63;
  const float* Tw = ws + OF_TW;
  float c[15], s[15];
#pragma unroll
  for (int k = 0; k < 15; ++k) {
    c[k] = Tw[(2*k)*256 + w0];
    s[k] = Tw[(2*k+1)*256 + w0];
  }
  __syncthreads();

  // ---- phase A ----
  {
    const int hl = t >> 3, kq = t & 7;
    const int h  = hc*32 + hl;
    const float chh = cst[h], shh = snt[h];
    float c1 = 1.f, s1 = 0.f;
    const int m2i = (240 * h) & 255;
    float c2 = cst[m2i], s2 = snt[m2i];
    float2 sr = {0.f,0.f}, si = {0.f,0.f};
    for (int j = 0; j < 16; ++j) {
      const float2 r1 = *(const float2*)&o1r[j*16 + kq*2];
      const float2 i1 = *(const float2*)&o1i[j*16 + kq*2];
      const float2 r2 = *(const float2*)&o2r[j*16 + kq*2];
      const float2 i2 = *(const float2*)&o2i[j*16 + kq*2];
      sr.x += r1.x*c1 - i1.x*s1 + r2.x*c2 - i2.x*s2;
      si.x += r1.x*s1 + i1.x*c1 + r2.x*s2 + i2.x*c2;
      sr.y += r1.y*c1 - i1.y*s1 + r2.y*c2 - i2.y*s2;
      si.y += r1.y*s1 + i1.y*c1 + r2.y*s2 + i2.y*c2;
      const float n1c = c1*chh - s1*shh, n1s = s1*chh + c1*shh;
      const float n2c = c2*chh - s2*shh, n2s = s2*chh + c2*shh;
      c1 = n1c; s1 = n1s; c2 = n2c; s2 = n2s;
    }
    *(float2*)&Sr[hl][kq*2] = sr;
    *(float2*)&Si[hl][kq*2] = si;
  }
  __syncthreads();

  // ---- phase B: radix-4 butterfly over ky mod 4 ----
  const int rg = t >> 6;               // 4 waves x 8 rows
  const float scale = 2.0f / 65536.0f;
  const size_t rowbase = ((size_t)bo*256 + hc*32 + rg*8) * 256;
#pragma unroll 2
  for (int r = 0; r < 8; ++r) {
    const int hl = rg*8 + r;
    const float4 a0 = *(const float4*)&Sr[hl][0];
    const float4 a1 = *(const float4*)&Sr[hl][4];
    const float4 a2 = *(const float4*)&Sr[hl][8];
    const float4 a3 = *(const float4*)&Sr[hl][12];
    const float4 b0 = *(const float4*)&Si[hl][0];
    const float4 b1 = *(const float4*)&Si[hl][4];
    const float4 b2 = *(const float4*)&Si[hl][8];
    const float4 b3 = *(const float4*)&Si[hl][12];

    float PA = 0.5f * a0.x;
    float PB = 0.f, PC = 0.f, PD = 0.f, QB = 0.f, QD = 0.f;
    PB += a0.y*c[0] - b0.y*s[0];   QB += a0.y*s[0] + b0.y*c[0];
    PC += a0.z*c[1] - b0.z*s[1];
    PD += a0.w*c[2] - b0.w*s[2];   QD += a0.w*s[2] + b0.w*c[2];
    PA += a1.x*c[3] - b1.x*s[3];
    PB += a1.y*c[4] - b1.y*s[4];   QB += a1.y*s[4] + b1.y*c[4];
    PC += a1.z*c[5] - b1.z*s[5];
    PD += a1.w*c[6] - b1.w*s[6];   QD += a1.w*s[6] + b1.w*c[6];
    PA += a2.x*c[7] - b2.x*s[7];
    PB += a2.y*c[8] - b2.y*s[8];   QB += a2.y*s[8] + b2.y*c[8];
    PC += a2.z*c[9] - b2.z*s[9];
    PD += a2.w*c[10] - b2.w*s[10]; QD += a2.w*s[10] + b2.w*c[10];
    PA += a3.x*c[11] - b3.x*s[11];
    PB += a3.y*c[12] - b3.y*s[12]; QB += a3.y*s[12] + b3.y*c[12];
    PC += a3.z*c[13] - b3.z*s[13];
    PD += a3.w*c[14] - b3.w*s[14]; QD += a3.w*s[14] + b3.w*c[14];

    const float T1 = PA + PC, T2 = PB + PD;
    const float T3 = PA - PC, T4 = QB - QD;
    const size_t ob = rowbase + (size_t)r*256 + w0;
    out[ob]       = (T1 + T2) * scale;
    out[ob + 64]  = (T3 - T4) * scale;
    out[ob + 128] = (T1 - T2) * scale;
    out[ob + 192] = (T3 + T4) * scale;
  }
}

extern "C" void kernel_launch(void* const* d_in, const int* in_sizes, int n_in,
                              void* d_out, int out_size, void* d_ws, size_t ws_size,
                              hipStream_t stream) {
  const float* x   = (const float*)d_in[0];
  const float* w1r = (const float*)d_in[1];
  const float* w1i = (const float*)d_in[2];
  const float* w2r = (const float*)d_in[3];
  const float* w2i = (const float*)d_in[4];
  float* out = (float*)d_out;
  float* ws  = (float*)d_ws;

  hipLaunchKernelGGL(k0_init,  dim3(31),    dim3(256), 0, stream, ws);
  hipLaunchKernelGGL(k1_dftw,  dim3(256),   dim3(256), 0, stream, x, ws);
  hipLaunchKernelGGL(k2_dfth,  dim3(256),   dim3(256), 0, stream, ws);
  hipLaunchKernelGGL(k3_mix,   dim3(64, 4), dim3(256), 0, stream, w1r, w1i, w2r, w2i, ws);
  hipLaunchKernelGGL(k45_idft, dim3(2048),  dim3(256), 0, stream, ws, out);
}

// Round 9
// 68.383 us; speedup vs baseline: 1.1156x; 1.1156x over previous
//
#include <hip/hip_runtime.h>

#define NB 4
#define NCI 64
#define NCO 64
#define NH 256
#define NW 256
#define NIMG (NB*NCI)      // 256
#define PLANE (NIMG*NH)    // 65536

// workspace offsets (in floats)
#define OF_COS 0
#define OF_SIN 256
#define OF_TW  512                      // [30][256] final-stage trig (ky=1..15 cos/sin)
#define OF_XS_RE (16384 + 32*PLANE)
#define OF_XS_IM (OF_XS_RE + PLANE)
#define OF_O1_RE (OF_XS_IM + PLANE)
#define OF_O1_IM (OF_O1_RE + PLANE)
#define OF_O2_RE (OF_O1_IM + PLANE)
#define OF_O2_IM (OF_O2_RE + PLANE)

// LDS plane layout for k12: xe/re planes at w*260, xo/im planes at +8 words
// (odd half-row shift keeps xe-vs-xo b128 reads 2-way bank aliased = free)
#define XEOFF(w) ((w)*260)
#define XOOFF(w) (16*260 + 8 + (w)*260)

// grid 31: block 0 -> cos/sin tables; blocks 1..30 -> one TW row each
__global__ __launch_bounds__(256) void k0_init(float* __restrict__ ws) {
  const int t = threadIdx.x, b = blockIdx.x;
  const double TP = 6.283185307179586;
  if (b == 0) {
    double a = TP * t / 256.0;
    ws[OF_COS + t] = (float)cos(a);
    ws[OF_SIN + t] = (float)sin(a);
  } else {
    const int p = b - 1;              // 0..29
    const int ky = (p >> 1) + 1;
    double a = TP * ((ky * t) & 255) / 256.0;
    ws[OF_TW + p*256 + t] = (p & 1) ? (float)sin(a) : (float)cos(a);
  }
}

// Fused stage 1+2, 1024 threads, grid 256 (1 img/block, 16 waves/CU).
// part 1: w-DFT, (w,w+128) fold at staging; 8 chunks x 16 folded cols.
//   compute map (wq=t&3, p=(t>>2)&1, kg=(t>>3)&1, tr=t>>4):
//   4 same-parity ky = p+8kg+2j (j=0..3) x 4 rows (tr*4..+3), w split 4 ways
//   across wq, merged via shfl_xor 1,2. Parity split -> each thread reads only
//   its xe OR xo plane (half the LDS reads of the R7 version).
// part 2: h-DFT, thread (ky=t&15, kx=(t>>4)&15, hh=t>>8) quarter h-sums,
//   float4 LDS reads, s2 reduce.
__global__ __launch_bounds__(1024) void k12_dft(const float* __restrict__ x,
                                                float* __restrict__ ws) {
  __shared__ float buf[8336];          // 16 xe + 16 xo planes (then re/im planes)
  __shared__ float cst[256], snt[256];
  __shared__ float2 s2[1024];
  const int t = threadIdx.x;
  const int img = blockIdx.x;

  if (t < 256) { cst[t] = ws[OF_COS + t]; snt[t] = ws[OF_SIN + t]; }

  const int sl = t & 3, row = t >> 2;                       // staging map
  const int wq = t & 3, p = (t >> 2) & 1;                   // compute map
  const int kg = (t >> 3) & 1, tr = t >> 4;
  int kyv[4];
#pragma unroll
  for (int j = 0; j < 4; ++j) kyv[j] = p + 8*kg + 2*j;

  __syncthreads();                     // cst/snt ready

  float cd[4], sd[4];
#pragma unroll
  for (int j = 0; j < 4; ++j) { cd[j] = cst[kyv[j]]; sd[j] = snt[kyv[j]]; }

  float ar[4][4], ai[4][4];            // [j][row]
#pragma unroll
  for (int j = 0; j < 4; ++j)
#pragma unroll
    for (int r = 0; r < 4; ++r) { ar[j][r] = 0.f; ai[j][r] = 0.f; }

  const float* xb = x + (size_t)img * 65536;
  float4 lo = *(const float4*)(xb + row*256 + sl*4);
  float4 hi = *(const float4*)(xb + row*256 + 128 + sl*4);

  const int pbase = p ? (16*260 + 8) : 0;

  for (int c = 0; c < 8; ++c) {
    __syncthreads();                   // prev chunk compute done
    buf[XEOFF(sl*4+0) + row] = lo.x + hi.x;
    buf[XEOFF(sl*4+1) + row] = lo.y + hi.y;
    buf[XEOFF(sl*4+2) + row] = lo.z + hi.z;
    buf[XEOFF(sl*4+3) + row] = lo.w + hi.w;
    buf[XOOFF(sl*4+0) + row] = lo.x - hi.x;
    buf[XOOFF(sl*4+1) + row] = lo.y - hi.y;
    buf[XOOFF(sl*4+2) + row] = lo.z - hi.z;
    buf[XOOFF(sl*4+3) + row] = lo.w - hi.w;
    __syncthreads();
    if (c < 7) {                       // T14: prefetch next chunk
      const int w0n = (c+1) * 16;
      lo = *(const float4*)(xb + row*256 + w0n + sl*4);
      hi = *(const float4*)(xb + row*256 + w0n + 128 + sl*4);
    }
    // rotation init at w0 = c*16 + wq*4 for each of the 4 ky chains
    float cc[4], sv[4];
#pragma unroll
    for (int j = 0; j < 4; ++j) {
      const int m = (kyv[j] * (c*16 + wq*4)) & 255;
      cc[j] = cst[m];
      sv[j] = snt[m];
    }
#pragma unroll
    for (int i = 0; i < 4; ++i) {
      const int wl = wq*4 + i;
      const float4 xs4 = *(const float4*)&buf[pbase + wl*260 + tr*4];
#pragma unroll
      for (int j = 0; j < 4; ++j) {
        ar[j][0] += xs4.x * cc[j];  ai[j][0] -= xs4.x * sv[j];
        ar[j][1] += xs4.y * cc[j];  ai[j][1] -= xs4.y * sv[j];
        ar[j][2] += xs4.z * cc[j];  ai[j][2] -= xs4.z * sv[j];
        ar[j][3] += xs4.w * cc[j];  ai[j][3] -= xs4.w * sv[j];
        const float nc = cc[j]*cd[j] - sv[j]*sd[j];
        const float ns = sv[j]*cd[j] + cc[j]*sd[j];
        cc[j] = nc; sv[j] = ns;
      }
    }
  }

  // merge w-quarters (wq = lane bits 0..1)
#pragma unroll
  for (int j = 0; j < 4; ++j)
#pragma unroll
    for (int r = 0; r < 4; ++r) {
      ar[j][r] += __shfl_xor(ar[j][r], 1);
      ar[j][r] += __shfl_xor(ar[j][r], 2);
      ai[j][r] += __shfl_xor(ai[j][r], 1);
      ai[j][r] += __shfl_xor(ai[j][r], 2);
    }
  __syncthreads();                     // chunk-7 reads done; buf reusable
  if (wq == 0) {
#pragma unroll
    for (int j = 0; j < 4; ++j) {
      const int ky = kyv[j];
      float4 sr; sr.x = ar[j][0]; sr.y = ar[j][1]; sr.z = ar[j][2]; sr.w = ar[j][3];
      float4 si; si.x = ai[j][0]; si.y = ai[j][1]; si.z = ai[j][2]; si.w = ai[j][3];
      *(float4*)&buf[XEOFF(ky) + tr*4] = sr;
      *(float4*)&buf[XOOFF(ky) + tr*4] = si;
    }
  }
  __syncthreads();

  // ---- part 2: h-DFT, quarter h-range per thread ----
  const int ky2 = t & 15, kx = (t >> 4) & 15, hh = t >> 8;
  const float cdk = cst[kx], sdk = snt[kx];
  const int m0 = (kx * hh * 64) & 255;
  float cR = cst[m0], sR = snt[m0];
  float arr = 0.f, aii = 0.f;
  const int be = XEOFF(ky2) + hh*64;
  const int bo = XOOFF(ky2) + hh*64;
#pragma unroll 4
  for (int hq = 0; hq < 16; ++hq) {
    const float4 xr = *(const float4*)&buf[be + hq*4];
    const float4 xi = *(const float4*)&buf[bo + hq*4];
    {
      arr += xr.x*cR + xi.x*sR;  aii += xi.x*cR - xr.x*sR;
      const float nc = cR*cdk - sR*sdk, ns = sR*cdk + cR*sdk; cR = nc; sR = ns;
    }
    {
      arr += xr.y*cR + xi.y*sR;  aii += xi.y*cR - xr.y*sR;
      const float nc = cR*cdk - sR*sdk, ns = sR*cdk + cR*sdk; cR = nc; sR = ns;
    }
    {
      arr += xr.z*cR + xi.z*sR;  aii += xi.z*cR - xr.z*sR;
      const float nc = cR*cdk - sR*sdk, ns = sR*cdk + cR*sdk; cR = nc; sR = ns;
    }
    {
      arr += xr.w*cR + xi.w*sR;  aii += xi.w*cR - xr.w*sR;
      const float nc = cR*cdk - sR*sdk, ns = sR*cdk + cR*sdk; cR = nc; sR = ns;
    }
  }
  s2[t].x = arr; s2[t].y = aii;
  __syncthreads();
  if (t < 256) {
    float xre = s2[t].x + s2[t+256].x + s2[t+512].x + s2[t+768].x;
    float xim = s2[t].y + s2[t+256].y + s2[t+512].y + s2[t+768].y;
    ws[OF_XS_RE + img*256 + t] = xre;
    ws[OF_XS_IM + img*256 + t] = xim;
  }
}

// Stage 3: o1/o2[b,o,m] = sum_i xs[b,i,m] * (wr + i wi)[i,o,m]
__global__ __launch_bounds__(256) void k3_mix(const float* __restrict__ w1r,
    const float* __restrict__ w1i, const float* __restrict__ w2r,
    const float* __restrict__ w2i, float* __restrict__ ws) {
  const int o  = blockIdx.x;     // 0..63
  const int mc = blockIdx.y;     // 0..3
  const int t  = threadIdx.x;    // 256
  const int b  = t >> 6;
  const int m  = (mc << 6) + (t & 63);
  const float* xsr = ws + OF_XS_RE;
  const float* xsi = ws + OF_XS_IM;
  float a1r=0.f, a1i=0.f, a2r=0.f, a2i=0.f;
#pragma unroll 4
  for (int i = 0; i < NCI; ++i) {
    const float xr = xsr[((b*NCI + i) << 8) + m];
    const float xi = xsi[((b*NCI + i) << 8) + m];
    const int wi = ((i*NCO + o) << 8) + m;
    const float p = w1r[wi], q = w1i[wi], u = w2r[wi], v = w2i[wi];
    a1r += xr*p - xi*q;
    a1i += xr*q + xi*p;
    a2r += xr*u - xi*v;
    a2i += xr*v + xi*u;
  }
  const int oi = ((b*NCO + o) << 8) + m;
  ws[OF_O1_RE + oi] = a1r;
  ws[OF_O1_IM + oi] = a1i;
  ws[OF_O2_RE + oi] = a2r;
  ws[OF_O2_IM + oi] = a2i;
}

// Fused stage 4+5 (R7-verbatim: grid 1024, best measured config).
// phase A: S[hl][ky] (complex, 64x16) into LDS; trig via dual rotation.
// phase B: radix-4 butterfly over ky mod 4 -> 4 columns per thread.
__global__ __launch_bounds__(256) void k45_idft(const float* __restrict__ ws,
                                                float* __restrict__ out) {
  __shared__ __align__(16) float o1r[256], o1i[256], o2r[256], o2i[256];
  __shared__ float cst[256], snt[256];
  __shared__ __align__(16) float Sr[64][20], Si[64][20];
  const int t  = threadIdx.x;
  const int bo = blockIdx.x >> 2;
  const int hc = blockIdx.x & 3;

  o1r[t] = ws[OF_O1_RE + bo*256 + t];
  o1i[t] = ws[OF_O1_IM + bo*256 + t];
  o2r[t] = ws[OF_O2_RE + bo*256 + t];
  o2i[t] = ws[OF_O2_IM + bo*256 + t];
  cst[t] = ws[OF_COS + t];
  snt[t] = ws[OF_SIN + t];

  const int w0 = t & 63;
  const float* Tw = ws + OF_TW;
  float c[15], s[15];
#pragma unroll
  for (int k = 0; k < 15; ++k) {
    c[k] = Tw[(2*k)*256 + w0];
    s[k] = Tw[(2*k+1)*256 + w0];
  }
  __syncthreads();

  // ---- phase A ----
  {
    const int hl = t >> 2, kq = t & 3;
    const int h  = hc*64 + hl;
    const float chh = cst[h], shh = snt[h];
    float c1 = 1.f, s1 = 0.f;
    const int m2i = (240 * h) & 255;
    float c2 = cst[m2i], s2 = snt[m2i];
    float4 sr = {0.f,0.f,0.f,0.f}, si = {0.f,0.f,0.f,0.f};
    for (int j = 0; j < 16; ++j) {
      const float4 r1 = *(const float4*)&o1r[j*16 + kq*4];
      const float4 i1 = *(const float4*)&o1i[j*16 + kq*4];
      const float4 r2 = *(const float4*)&o2r[j*16 + kq*4];
      const float4 i2 = *(const float4*)&o2i[j*16 + kq*4];
      sr.x += r1.x*c1 - i1.x*s1 + r2.x*c2 - i2.x*s2;
      si.x += r1.x*s1 + i1.x*c1 + r2.x*s2 + i2.x*c2;
      sr.y += r1.y*c1 - i1.y*s1 + r2.y*c2 - i2.y*s2;
      si.y += r1.y*s1 + i1.y*c1 + r2.y*s2 + i2.y*c2;
      sr.z += r1.z*c1 - i1.z*s1 + r2.z*c2 - i2.z*s2;
      si.z += r1.z*s1 + i1.z*c1 + r2.z*s2 + i2.z*c2;
      sr.w += r1.w*c1 - i1.w*s1 + r2.w*c2 - i2.w*s2;
      si.w += r1.w*s1 + i1.w*c1 + r2.w*s2 + i2.w*c2;
      const float n1c = c1*chh - s1*shh, n1s = s1*chh + c1*shh;
      const float n2c = c2*chh - s2*shh, n2s = s2*chh + c2*shh;
      c1 = n1c; s1 = n1s; c2 = n2c; s2 = n2s;
    }
    *(float4*)&Sr[hl][kq*4] = sr;
    *(float4*)&Si[hl][kq*4] = si;
  }
  __syncthreads();

  // ---- phase B: radix-4 butterfly over ky mod 4 ----
  const int rg = t >> 6;
  const float scale = 2.0f / 65536.0f;
  const size_t rowbase = ((size_t)bo*256 + hc*64 + rg*16) * 256;
#pragma unroll 2
  for (int r = 0; r < 16; ++r) {
    const int hl = rg*16 + r;
    const float4 a0 = *(const float4*)&Sr[hl][0];
    const float4 a1 = *(const float4*)&Sr[hl][4];
    const float4 a2 = *(const float4*)&Sr[hl][8];
    const float4 a3 = *(const float4*)&Sr[hl][12];
    const float4 b0 = *(const float4*)&Si[hl][0];
    const float4 b1 = *(const float4*)&Si[hl][4];
    const float4 b2 = *(const float4*)&Si[hl][8];
    const float4 b3 = *(const float4*)&Si[hl][12];

    float PA = 0.5f * a0.x;
    float PB = 0.f, PC = 0.f, PD = 0.f, QB = 0.f, QD = 0.f;
    PB += a0.y*c[0] - b0.y*s[0];   QB += a0.y*s[0] + b0.y*c[0];
    PC += a0.z*c[1] - b0.z*s[1];
    PD += a0.w*c[2] - b0.w*s[2];   QD += a0.w*s[2] + b0.w*c[2];
    PA += a1.x*c[3] - b1.x*s[3];
    PB += a1.y*c[4] - b1.y*s[4];   QB += a1.y*s[4] + b1.y*c[4];
    PC += a1.z*c[5] - b1.z*s[5];
    PD += a1.w*c[6] - b1.w*s[6];   QD += a1.w*s[6] + b1.w*c[6];
    PA += a2.x*c[7] - b2.x*s[7];
    PB += a2.y*c[8] - b2.y*s[8];   QB += a2.y*s[8] + b2.y*c[8];
    PC += a2.z*c[9] - b2.z*s[9];
    PD += a2.w*c[10] - b2.w*s[10]; QD += a2.w*s[10] + b2.w*c[10];
    PA += a3.x*c[11] - b3.x*s[11];
    PB += a3.y*c[12] - b3.y*s[12]; QB += a3.y*s[12] + b3.y*c[12];
    PC += a3.z*c[13] - b3.z*s[13];
    PD += a3.w*c[14] - b3.w*s[14]; QD += a3.w*s[14] + b3.w*c[14];

    const float T1 = PA + PC, T2 = PB + PD;
    const float T3 = PA - PC, T4 = QB - QD;
    const size_t ob = rowbase + (size_t)r*256 + w0;
    out[ob]       = (T1 + T2) * scale;
    out[ob + 64]  = (T3 - T4) * scale;
    out[ob + 128] = (T1 - T2) * scale;
    out[ob + 192] = (T3 + T4) * scale;
  }
}

extern "C" void kernel_launch(void* const* d_in, const int* in_sizes, int n_in,
                              void* d_out, int out_size, void* d_ws, size_t ws_size,
                              hipStream_t stream) {
  const float* x   = (const float*)d_in[0];
  const float* w1r = (const float*)d_in[1];
  const float* w1i = (const float*)d_in[2];
  const float* w2r = (const float*)d_in[3];
  const float* w2i = (const float*)d_in[4];
  float* out = (float*)d_out;
  float* ws  = (float*)d_ws;

  hipLaunchKernelGGL(k0_init,  dim3(31),    dim3(256),  0, stream, ws);
  hipLaunchKernelGGL(k12_dft,  dim3(256),   dim3(1024), 0, stream, x, ws);
  hipLaunchKernelGGL(k3_mix,   dim3(64, 4), dim3(256),  0, stream, w1r, w1i, w2r, w2i, ws);
  hipLaunchKernelGGL(k45_idft, dim3(1024),  dim3(256),  0, stream, ws, out);
}